// Round 4
// baseline (1173.839 us; speedup 1.0000x reference)
//
#include <hip/hip_runtime.h>
#include <stdint.h>

#define B_  2
#define H_  4
#define T_  2048
#define N_  4096
#define BH  8          // B_*H_

// 256x256 tile, BK=64, 8 waves (2Mx4N), 4-phase reads-ahead pipelined schedule
#define BM 256
#define BN 256
#define BK 64

#define ROPE_BLOCKS  ((BH * (long)T_ * N_) / (8 * 256))   // 32768
#define TRANS_BLOCKS ((T_ / 64) * (N_ / 64) * BH)         // 16384

typedef __attribute__((ext_vector_type(8))) short  short8;
typedef __attribute__((ext_vector_type(4))) float  floatx4;

// ---- helpers ---------------------------------------------------------------

__device__ __forceinline__ unsigned short f2bf(float x) {
  union { float f; unsigned u; } un; un.f = x;
  unsigned r = un.u + 0x7FFFu + ((un.u >> 16) & 1u);   // round-to-nearest-even
  return (unsigned short)(r >> 16);
}

__device__ __forceinline__ void async_copy16(const void* g, void* l) {
  __builtin_amdgcn_global_load_lds(
      (const __attribute__((address_space(1))) unsigned int*)g,
      (__attribute__((address_space(3))) unsigned int*)l,
      16, 0, 0);
}

// ---- fused prep: RoPE(Q)->bf16  and  V -> Vt (bf16), block-partitioned -----
__global__ __launch_bounds__(256)
void prep_kernel(const float* __restrict__ Q, unsigned short* __restrict__ QR,
                 const float* __restrict__ V, unsigned short* __restrict__ Vt) {
  __shared__ float tile[64][65];
  const int bid = (int)blockIdx.x;

  if (bid < (int)ROPE_BLOCKS) {
    // ---- RoPE(Q) + cast ----
    const long e0 = ((long)bid * 256 + threadIdx.x) * 8;
    const float4 v0 = *(const float4*)(Q + e0);
    const float4 v1 = *(const float4*)(Q + e0 + 4);
    const int   n0 = (int)(e0 & (N_ - 1));
    const float t  = (float)((int)((e0 >> 12) & (T_ - 1)));
    float vv[8] = {v0.x, v0.y, v0.z, v0.w, v1.x, v1.y, v1.z, v1.w};
    union { short8 v; unsigned short u[8]; } o;
#pragma unroll
    for (int p = 0; p < 4; ++p) {
      const int n = n0 + 2 * p;
      const float freq = exp2f(-(float)n * (1.0f / 256.0f)) * 0.15915494309189535f;
      const float ph = t * freq;
      const float fr = ph - floorf(ph);
      const float s = __builtin_amdgcn_sinf(fr);
      const float c = __builtin_amdgcn_cosf(fr);
      o.u[2 * p]     = f2bf(vv[2 * p] * c - vv[2 * p + 1] * s);
      o.u[2 * p + 1] = f2bf(vv[2 * p + 1] * c + vv[2 * p] * s);
    }
    *(short8*)(QR + e0) = o.v;
  } else {
    // ---- V transpose + cast, vectorized both sides ----
    const int tb = bid - (int)ROPE_BLOCKS;
    const int sxi = tb & 31;                 // T_/64 = 32
    const int nyi = (tb >> 5) & 63;          // N_/64 = 64
    const long bh = tb >> 11;
    const float* Vb = V + bh * (long)T_ * N_;
    unsigned short* Vtb = Vt + bh * (long)N_ * T_;
    const int s0 = sxi * 64;
    const int n0 = nyi * 64;
    const int c = threadIdx.x & 15;          // n-quad 0..15
    const int r = threadIdx.x >> 4;          // s-row 0..15
#pragma unroll
    for (int i = 0; i < 4; ++i) {
      const float4 v = *(const float4*)(Vb + (long)(s0 + r + 16 * i) * N_ + n0 + c * 4);
      tile[r + 16 * i][c * 4 + 0] = v.x;
      tile[r + 16 * i][c * 4 + 1] = v.y;
      tile[r + 16 * i][c * 4 + 2] = v.z;
      tile[r + 16 * i][c * 4 + 3] = v.w;
    }
    __syncthreads();
    const int rn = threadIdx.x >> 3;         // n 0..31
    const int cs = threadIdx.x & 7;          // s-octet 0..7
#pragma unroll
    for (int i = 0; i < 2; ++i) {
      const int n = rn + 32 * i;
      union { short8 v; unsigned short u[8]; } o;
#pragma unroll
      for (int k = 0; k < 8; ++k) o.u[k] = f2bf(tile[cs * 8 + k][n]);
      *(short8*)(Vtb + (long)(n0 + n) * T_ + s0 + cs * 8) = o.v;
    }
  }
}

// ---- 256^2 pipelined GEMM (B^T layout): C = alpha * A @ B^T ----------------
// LDS: per operand 256x64 bf16, two 128-row halves of 16 KiB; lane-linear dest
// (global_load_lds), st-swizzle byte^=((row&7)<<4) via pre-swizzled global src
// + swizzled ds_read addr (rule #21).  A-par0 @0 (h1 +16384), B-par0 @32768,
// parity toggle ^0x10000.
//
// Reads-one-phase-ahead schedule, quadrant order (0,0),(0,1),(1,0),(1,1):
//   ph0: STAGE A(t+1)h0; MFMA(0,0)[a=A0,b0];       read b1=B1(t)
//   ph1: STAGE A(t+1)h1; MFMA(0,1)[a=A0,b1];       read a=A1(t)
//   ph2: STAGE B(t+2)h0; vmcnt(2); BARRIER;        (gates next-parity reads)
//        MFMA(1,0)[a=A1,b0];                       read b0=B0(t+1)
//   ph3: STAGE B(t+2)h1; MFMA(1,1)[a=A1,b1];       read a=A0(t+1)
// Every phase closes with: sched_barrier(0) (pins reads below MFMA -> register
// reuse, no 2x frag arrays); asm lgkmcnt(0) (pins ds_reads before the barrier —
// the r2 race was reads sinking past a bare s_barrier); s_barrier.
// vmcnt(2)+barrier at ph2 is the only cross-wave stage-landing gate (vmcnt only
// tracks the issuing wave's loads, so the barrier is mandatory before reads).
template<int QI, int QJ>
__device__ __forceinline__ void mfma_quad(floatx4 (&acc)[8][4], const short8* a, const short8* b) {
#pragma unroll
  for (int s = 0; s < 2; ++s)
#pragma unroll
    for (int f = 0; f < 4; ++f)
#pragma unroll
      for (int c = 0; c < 2; ++c)
        acc[QI * 4 + f][QJ * 2 + c] = __builtin_amdgcn_mfma_f32_16x16x32_bf16(
            a[f * 2 + s], b[c * 2 + s], acc[QI * 4 + f][QJ * 2 + c], 0, 0, 0);
}

template <typename OutT>
__global__ __launch_bounds__(512, 2)
void gemm_bt8(const unsigned short* __restrict__ A, const unsigned short* __restrict__ B,
              OutT* __restrict__ C, int M, int Nc, int K, float alpha,
              long sA, long sB, long sC)
{
  __shared__ unsigned short smem[4][16384];   // 128 KiB
  char* smemb = (char*)smem;

  // T1: bijective XCD-aware block swizzle (nwg % 8 == 0 for both GEMMs)
  const int nx = (int)gridDim.x, ny = (int)gridDim.y;
  const int nwg = nx * ny * (int)gridDim.z;
  const int idx = (int)blockIdx.x + nx * ((int)blockIdx.y + ny * (int)blockIdx.z);
  const int wg = ((nwg & 7) == 0) ? ((idx & 7) * (nwg >> 3) + (idx >> 3)) : idx;
  const int bx = wg % nx;
  const int by = (wg / nx) % ny;
  const int bz = wg / (nx * ny);

  const unsigned short* Ab = A + bz * sA;
  const unsigned short* Bb = B + bz * sB;
  OutT* Cb = C + bz * sC;
  const int tM = by * BM, tN = bx * BN;

  const int tid  = (int)threadIdx.x;
  const int lane = tid & 63;
  const int wave = tid >> 6;
  const int wm = wave >> 2;                   // 0..1  (128-row slab)
  const int wn = wave & 3;                    // 0..3  (64-col slab)
  const int lr = lane & 15;
  const int lk = (lane >> 4) * 8;

  // strength-reduced ds_read bases (r2/r3-validated): swizzle XOR term
  // (r&7)<<4 == (lane&7)<<4 is row-invariant per lane.
  const unsigned swz   = (unsigned)(lane & 7) << 4;
  const unsigned lowA0 = ((unsigned)(lk * 2)     ) ^ swz;
  const unsigned lowA1 = ((unsigned)(lk * 2) + 64) ^ swz;
  const unsigned aB4   = (unsigned)wm * 16384u + (unsigned)lr * 128u;
  const unsigned bB4   = 32768u + (unsigned)(wn >> 1) * 16384u
                       + (unsigned)(wn & 1) * 8192u + (unsigned)lr * 128u;

  // staging geometry: linear LDS dest + inverse-swizzled source (rule #21)
  const int sr = wave * 8 + (lane >> 3);
  const int sc = ((((lane & 7) * 16) ^ ((lane >> 3) << 4)) >> 1);
  const unsigned short* gA = Ab + (long)(tM + sr) * K + sc;
  const unsigned short* gB = Bb + (long)(tN + sr) * K + sc;
  const int NT = K / BK;

  #define STAGE2(gbase, kt, h, ldst) do {                                          \
    const unsigned short* _g = (gbase) + (long)(kt) * 64 + (long)((h) * 128) * K;  \
    async_copy16(_g,                (char*)(ldst) + wave * 1024);                  \
    async_copy16(_g + (long)64 * K, (char*)(ldst) + 8192 + wave * 1024);           \
  } while (0)

  // prologue: B(0) | A(0) | B(1); drain all but B(1)'s 4 loads
  STAGE2(gB, 0, 0, smemb + 32768);
  STAGE2(gB, 0, 1, smemb + 32768 + 16384);
  STAGE2(gA, 0, 0, smemb + 0);
  STAGE2(gA, 0, 1, smemb + 16384);
  const int k1 = (NT > 1) ? 1 : 0;
  STAGE2(gB, k1, 0, smemb + 65536 + 32768);
  STAGE2(gB, k1, 1, smemb + 65536 + 32768 + 16384);
  asm volatile("s_waitcnt vmcnt(4)" ::: "memory");
  __builtin_amdgcn_s_barrier();

  floatx4 acc[8][4] = {};
  short8 a[8], b0[4], b1[4];

  // preload a = A0(0), b0 = B0(0) from parity-0 (drain handled by ph0's close)
  {
    const char* pa0 = smemb + (aB4 + lowA0);
    const char* pa1 = smemb + (aB4 + lowA1);
    const char* pb0 = smemb + (bB4 + lowA0);
    const char* pb1 = smemb + (bB4 + lowA1);
#pragma unroll
    for (int f = 0; f < 4; ++f) {
      a[f * 2 + 0] = *(const short8*)(pa0 + f * 2048);
      a[f * 2 + 1] = *(const short8*)(pa1 + f * 2048);
    }
#pragma unroll
    for (int c = 0; c < 2; ++c) {
      b0[c * 2 + 0] = *(const short8*)(pb0 + c * 2048);
      b0[c * 2 + 1] = *(const short8*)(pb1 + c * 2048);
    }
  }

  for (int t = 0; t < NT; ++t) {
    const unsigned par  = (unsigned)(t & 1) << 16;
    const unsigned parn = par ^ 0x10000u;
    const char* pa0c = smemb + (par + aB4 + lowA0);   // current-tile A
    const char* pa1c = smemb + (par + aB4 + lowA1);
    const char* pb0c = smemb + (par + bB4 + lowA0);   // current-tile B
    const char* pb1c = smemb + (par + bB4 + lowA1);
    const char* pa0n = smemb + (parn + aB4 + lowA0);  // next-tile A
    const char* pa1n = smemb + (parn + aB4 + lowA1);
    const char* pb0n = smemb + (parn + bB4 + lowA0);  // next-tile B
    const char* pb1n = smemb + (parn + bB4 + lowA1);
    const int ktA = (t + 1 < NT) ? t + 1 : NT - 1;    // tail loads clamped:
    const int ktB = (t + 2 < NT) ? t + 2 : NT - 1;    // never read, counts uniform

    // ---- phase 0: MFMA(0,0) [A rows 0-63 x B cols 0-31]; read b1 = B1(t)
    STAGE2(gA, ktA, 0, smemb + parn);
    __builtin_amdgcn_s_setprio(1);
    mfma_quad<0, 0>(acc, a, b0);
    __builtin_amdgcn_s_setprio(0);
    __builtin_amdgcn_sched_barrier(0);
#pragma unroll
    for (int c = 0; c < 2; ++c) {
      b1[c * 2 + 0] = *(const short8*)(pb0c + 4096 + c * 2048);
      b1[c * 2 + 1] = *(const short8*)(pb1c + 4096 + c * 2048);
    }
    asm volatile("s_waitcnt lgkmcnt(0)" ::: "memory");
    __builtin_amdgcn_s_barrier();

    // ---- phase 1: MFMA(0,1) [A0 x B cols 32-63]; read a = A1(t)
    STAGE2(gA, ktA, 1, smemb + parn + 16384);
    __builtin_amdgcn_s_setprio(1);
    mfma_quad<0, 1>(acc, a, b1);
    __builtin_amdgcn_s_setprio(0);
    __builtin_amdgcn_sched_barrier(0);
#pragma unroll
    for (int f = 0; f < 4; ++f) {
      a[f * 2 + 0] = *(const short8*)(pa0c + 8192 + f * 2048);
      a[f * 2 + 1] = *(const short8*)(pa1c + 8192 + f * 2048);
    }
    asm volatile("s_waitcnt lgkmcnt(0)" ::: "memory");
    __builtin_amdgcn_s_barrier();

    // ---- phase 2: gate next-parity; MFMA(1,0) [A1 x B0]; read b0 = B0(t+1)
    STAGE2(gB, ktB, 0, smemb + par + 32768);
    asm volatile("s_waitcnt vmcnt(2)" ::: "memory");   // A(t+1), B(t+1) landed
    __builtin_amdgcn_s_barrier();                      // ...for ALL waves
    __builtin_amdgcn_s_setprio(1);
    mfma_quad<1, 0>(acc, a, b0);
    __builtin_amdgcn_s_setprio(0);
    __builtin_amdgcn_sched_barrier(0);
#pragma unroll
    for (int c = 0; c < 2; ++c) {
      b0[c * 2 + 0] = *(const short8*)(pb0n + c * 2048);
      b0[c * 2 + 1] = *(const short8*)(pb1n + c * 2048);
    }
    asm volatile("s_waitcnt lgkmcnt(0)" ::: "memory");
    __builtin_amdgcn_s_barrier();

    // ---- phase 3: MFMA(1,1) [A1 x B1]; read a = A0(t+1)
    STAGE2(gB, ktB, 1, smemb + par + 32768 + 16384);
    __builtin_amdgcn_s_setprio(1);
    mfma_quad<1, 1>(acc, a, b1);
    __builtin_amdgcn_s_setprio(0);
    __builtin_amdgcn_sched_barrier(0);
#pragma unroll
    for (int f = 0; f < 4; ++f) {
      a[f * 2 + 0] = *(const short8*)(pa0n + f * 2048);
      a[f * 2 + 1] = *(const short8*)(pa1n + f * 2048);
    }
    asm volatile("s_waitcnt lgkmcnt(0)" ::: "memory");
    __builtin_amdgcn_s_barrier();
  }
  #undef STAGE2

  // epilogue: D mapping col = lane&15, row = (lane>>4)*4 + r
  const int crow = (lane >> 4) * 4;
  const int ccol = lane & 15;
#pragma unroll
  for (int f = 0; f < 8; ++f)
#pragma unroll
    for (int c = 0; c < 4; ++c)
#pragma unroll
      for (int r = 0; r < 4; ++r) {
        const long row = tM + wm * 128 + f * 16 + crow + r;
        const long col = tN + wn * 64 + c * 16 + ccol;
        const float v = acc[f][c][r] * alpha;
        OutT* p = &Cb[row * (long)Nc + col];
        if constexpr (sizeof(OutT) == 2) *p = (OutT)f2bf(v);
        else                             *p = (OutT)v;
      }
}

// ---- launch ----------------------------------------------------------------
extern "C" void kernel_launch(void* const* d_in, const int* in_sizes, int n_in,
                              void* d_out, int out_size, void* d_ws, size_t ws_size,
                              hipStream_t stream) {
  const float* Q = (const float*)d_in[0];
  // d_in[1] (K) is unused by the reference.
  const float* V = (const float*)d_in[2];
  float* O = (float*)d_out;

  // workspace layout: QRb (134MB) | Vtb (134MB) | S (64MB)  => ~320 MiB
  unsigned short* QRb = (unsigned short*)d_ws;
  unsigned short* Vtb = QRb + (size_t)BH * T_ * N_;
  unsigned short* S   = Vtb + (size_t)BH * T_ * N_;

  // 1+2. fused: RoPE(Q) -> bf16  and  V -> Vt (bf16)
  prep_kernel<<<(int)(ROPE_BLOCKS + TRANS_BLOCKS), 256, 0, stream>>>(Q, QRb, V, Vtb);
  // 3. S = (1/64) * QR @ QR^T   [per bh: 2048x2048, K=4096]
  gemm_bt8<unsigned short><<<dim3(T_ / BN, T_ / BM, BH), 512, 0, stream>>>(
      QRb, QRb, S, T_, T_, N_, 1.0f / 64.0f,
      (long)T_ * N_, (long)T_ * N_, (long)T_ * T_);
  // 4. O = S @ Vt^T             [per bh: 2048x4096, K=2048]
  gemm_bt8<float><<<dim3(N_ / BN, T_ / BM, BH), 512, 0, stream>>>(
      S, Vtb, O, T_, N_, T_, 1.0f,
      (long)T_ * T_, (long)N_ * T_, (long)T_ * N_);
}